// Round 12
// baseline (143.890 us; speedup 1.0000x reference)
//
#include <hip/hip_runtime.h>

// AdaPT_Linear: per-tensor int8 quantized linear.
// out = (qx @ qw^T).f32 / (sa*sw) + qb.f32/sb
// x: [16384,1024] f32, w: [1024,1024] f32, b: [1024] f32, out: [16384,1024] f32

#define M_ROWS 16384
#define K_DIM  1024
#define N_OUT  1024

typedef int v4i __attribute__((ext_vector_type(4)));
typedef float v4f __attribute__((ext_vector_type(4)));

__device__ __forceinline__ void gload_lds16(const void* g, void* l) {
  __builtin_amdgcn_global_load_lds(
      (const __attribute__((address_space(1))) void*)g,
      (__attribute__((address_space(3))) void*)l, 16, 0, 0);
}

__device__ __forceinline__ float block_reduce_max4(float m, float* red) {
#pragma unroll
  for (int off = 32; off > 0; off >>= 1)
    m = fmaxf(m, __shfl_down(m, off));
  const int wid = threadIdx.x >> 6, lane = threadIdx.x & 63;
  if (lane == 0) red[wid] = m;
  __syncthreads();
  float r = fmaxf(fmaxf(red[0], red[1]), fmaxf(red[2], red[3]));
  __syncthreads();
  return r;
}

// fused: blocks [0,2048) reduce x -> px, blocks [2048,2304) reduce w -> pw
__global__ void amax_both(const float* __restrict__ x, const float* __restrict__ wsrc,
                          float* __restrict__ px, float* __restrict__ pw) {
  __shared__ float red[4];
  const bool isx = blockIdx.x < 2048;
  const float* src = isx ? x : wsrc;
  const int n4   = isx ? (M_ROWS * K_DIM / 4) : (N_OUT * K_DIM / 4);
  const int nblk = isx ? 2048 : 256;
  const int bidl = isx ? blockIdx.x : blockIdx.x - 2048;
  float m = 0.0f;
  const int stride = nblk * 256;
  for (int idx = bidl * 256 + threadIdx.x; idx < n4; idx += stride) {
    float4 v = ((const float4*)src)[idx];
    m = fmaxf(m, fmaxf(fmaxf(fabsf(v.x), fabsf(v.y)), fmaxf(fabsf(v.z), fabsf(v.w))));
  }
  float r = block_reduce_max4(m, red);
  if (threadIdx.x == 0) (isx ? px : pw)[bidl] = r;
}

__global__ void finalize_kernel(const float* __restrict__ px, int npx,
                                const float* __restrict__ pw, int npw,
                                const float* __restrict__ bias,
                                float* __restrict__ amax,
                                float* __restrict__ bdeq) {
  __shared__ float red[4];
  const int tid = threadIdx.x;

  float m = 0.0f;
  for (int i = tid; i < npx; i += 256) m = fmaxf(m, px[i]);
  float rx = block_reduce_max4(m, red);

  m = 0.0f;
  for (int i = tid; i < npw; i += 256) m = fmaxf(m, pw[i]);
  float rw = block_reduce_max4(m, red);

  float4 bv = ((const float4*)bias)[tid];  // 256*4 == 1024 exactly
  m = fmaxf(fmaxf(fabsf(bv.x), fabsf(bv.y)), fmaxf(fabsf(bv.z), fabsf(bv.w)));
  float rb = block_reduce_max4(m, red);

  if (rx == 0.0f) rx = 1.0f;
  if (rw == 0.0f) rw = 1.0f;
  if (rb == 0.0f) rb = 1.0f;
  if (tid == 0) {
    amax[0] = rx;
    amax[1] = rw;
    amax[2] = rb;
  }
  const float sb = 127.0f / rb;
  float4 q;
  q.x = fminf(fmaxf(rintf(sb * bv.x), -127.0f), 127.0f) / sb;
  q.y = fminf(fmaxf(rintf(sb * bv.y), -127.0f), 127.0f) / sb;
  q.z = fminf(fmaxf(rintf(sb * bv.z), -127.0f), 127.0f) / sb;
  q.w = fminf(fmaxf(rintf(sb * bv.w), -127.0f), 127.0f) / sb;
  ((float4*)bdeq)[tid] = q;
}

// fused: blocks [0,2048) quantize x -> qx, [2048,2304) w -> qw
__global__ void quant_both(const float* __restrict__ x, const float* __restrict__ wsrc,
                           signed char* __restrict__ qx, signed char* __restrict__ qw,
                           const float* __restrict__ amax) {
  const bool isx = blockIdx.x < 2048;
  const float* src = isx ? x : wsrc;
  signed char* dst = isx ? qx : qw;
  const int n4   = isx ? (M_ROWS * K_DIM / 4) : (N_OUT * K_DIM / 4);
  const int nblk = isx ? 2048 : 256;
  const int bidl = isx ? blockIdx.x : blockIdx.x - 2048;
  const float s = 127.0f / amax[isx ? 0 : 1];
  const int stride = nblk * 256;
  for (int idx = bidl * 256 + threadIdx.x; idx < n4; idx += stride) {
    float4 v = ((const float4*)src)[idx];
    int q0 = (int)fminf(fmaxf(rintf(s * v.x), -127.0f), 127.0f);
    int q1 = (int)fminf(fmaxf(rintf(s * v.y), -127.0f), 127.0f);
    int q2 = (int)fminf(fmaxf(rintf(s * v.z), -127.0f), 127.0f);
    int q3 = (int)fminf(fmaxf(rintf(s * v.w), -127.0f), 127.0f);
    unsigned int packed = (q0 & 0xff) | ((q1 & 0xff) << 8) |
                          ((q2 & 0xff) << 16) | ((q3 & 0xff) << 24);
    ((unsigned int*)dst)[idx] = packed;
  }
}

// ---------------------------------------------------------------------------
// ABLATION ROUND. gemm_t<MODE,REPS>:
//  MODE 0: full R9 kernel (2-phase dbuf staging + MFMA + nt-store epilogue).
//  MODE 1: staging skeleton only — STG/VM/BAR/ds_read, fragments kept live
//          via asm sinks (rule #17), no MFMA, no stores. x REPS.
//  MODE 2: MFMA core only — ds_read(uninit LDS)+MFMA+barriers, no VMEM,
//          acc asm-sunk, no stores. x REPS.
// REPS inflate diagnostic dispatches past the ~40us fill threshold so they
// appear in rocprof top-5; per-piece time = dur/REPS.
// ---------------------------------------------------------------------------
#define NKT 16

template <int MODE, int REPS>
__global__ __launch_bounds__(256, 2) void gemm_t(
    const signed char* __restrict__ qx, const signed char* __restrict__ qw,
    const float* __restrict__ amax, const float* __restrict__ bdeq,
    float* __restrict__ out) {
  __shared__ char lds[49152];  // buf0: A 16K @0, B 8K @16384; buf1 @24576

  const int tid  = threadIdx.x;
  const int w    = tid >> 6;
  const int lane = tid & 63;
  const int wm = w >> 1;
  const int wn = w & 1;
  const int fr = lane & 15;
  const int q  = lane >> 4;

  const int bid = blockIdx.x;
  const int wg  = (bid & 7) * 64 + (bid >> 3);
  const int Mbase = (wg >> 3) * 256;
  const int Nbase = (wg & 7) * 128;

  const signed char* gA = qx + (size_t)Mbase * K_DIM;
  const signed char* gB = qw + (size_t)Nbase * K_DIM;

  const int srow = tid >> 2;
  const int scol = ((tid & 3) ^ ((tid >> 3) & 3)) << 4;
  const int u0    = (q ^ ((fr >> 1) & 3)) << 4;
  const int aoffA = fr * 64 + u0;
  const int aoffB = fr * 64 + u0;

  const float inv_denom = (amax[0] * amax[1]) * (1.0f / 16129.0f);

  v4i acc[8][4] = {};
  v4i Ar[8], Br[4];

#define STG(BUF, T)                                                            \
  do {                                                                         \
    const int _k0 = (T)*64 + scol;                                             \
    char* _la = lds + (BUF)*24576;                                             \
    char* _lb = _la + 16384;                                                   \
    _Pragma("unroll") for (int i = 0; i < 4; ++i)                              \
      gload_lds16(gA + (size_t)(i * 64 + srow) * K_DIM + _k0,                  \
                  _la + i * 4096 + tid * 16);                                  \
    _Pragma("unroll") for (int i = 0; i < 2; ++i)                              \
      gload_lds16(gB + (size_t)(i * 64 + srow) * K_DIM + _k0,                  \
                  _lb + i * 4096 + tid * 16);                                  \
  } while (0)

#define VM(N) asm volatile("s_waitcnt vmcnt(" #N ")" ::: "memory")

  for (int rep = 0; rep < REPS; ++rep) {
    if constexpr (MODE != 2) STG(0, 0);
    int cur = 0;
    for (int kt = 0; kt < NKT; ++kt) {
      if constexpr (MODE != 2) {
        if (kt + 1 < NKT) {
          STG(cur ^ 1, kt + 1);
          VM(6);
        } else {
          VM(0);
        }
      }
      __builtin_amdgcn_s_barrier();

      const char* _A = lds + cur * 24576 + wm * 8192;
      const char* _B = lds + cur * 24576 + 16384 + wn * 4096;
#pragma unroll
      for (int f = 0; f < 8; ++f)
        Ar[f] = *(const v4i*)(_A + aoffA + f * 1024);
#pragma unroll
      for (int g = 0; g < 4; ++g)
        Br[g] = *(const v4i*)(_B + aoffB + g * 1024);

      if constexpr (MODE == 1) {
        // keep ds_reads live without consuming them (rule #17)
#pragma unroll
        for (int f = 0; f < 8; ++f) asm volatile("" ::"v"(Ar[f][0]));
#pragma unroll
        for (int g = 0; g < 4; ++g) asm volatile("" ::"v"(Br[g][0]));
      } else {
#pragma unroll
        for (int f = 0; f < 8; ++f)
#pragma unroll
          for (int g = 0; g < 4; ++g)
            acc[f][g] = __builtin_amdgcn_mfma_i32_16x16x64_i8(Ar[f], Br[g],
                                                              acc[f][g], 0, 0, 0);
      }

      asm volatile("s_waitcnt lgkmcnt(0)" ::: "memory");
      __builtin_amdgcn_s_barrier();
      cur ^= 1;
    }
  }
#undef STG

  if constexpr (MODE == 2) {
    // keep the MFMA chain live; no stores
#pragma unroll
    for (int f = 0; f < 8; ++f)
#pragma unroll
      for (int g = 0; g < 4; ++g) asm volatile("" ::"v"(acc[f][g][0]));
  }
  if constexpr (MODE != 0) return;

  // ---------------- epilogue (MODE 0): LDS transpose + nt stores -----------
  __syncthreads();

  float bdq[4];
#pragma unroll
  for (int g = 0; g < 4; ++g) bdq[g] = bdeq[Nbase + wn * 64 + g * 16 + fr];

  float* lws = (float*)(lds + w * 12288);  // 16x66 f32 per wave

  const int erow = lane >> 4;
  const int ecg  = lane & 15;
  float* const orow_base = out + (size_t)(Mbase + wm * 128) * N_OUT +
                           (Nbase + wn * 64) + ecg * 4;

#pragma unroll
  for (int f = 0; f < 8; ++f) {
#pragma unroll
    for (int g = 0; g < 4; ++g)
#pragma unroll
      for (int i = 0; i < 4; ++i)
        lws[(q * 4 + i) * 66 + g * 16 + fr] =
            (float)acc[f][g][i] * inv_denom + bdq[g];
    asm volatile("s_waitcnt lgkmcnt(0)" ::: "memory");
#pragma unroll
    for (int t = 0; t < 4; ++t) {
      const int r16 = t * 4 + erow;
      v4f v = *(const v4f*)&lws[r16 * 66 + ecg * 4];
      __builtin_nontemporal_store(
          v, (v4f*)(orow_base + (size_t)(f * 16 + r16) * N_OUT));
    }
    asm volatile("s_waitcnt lgkmcnt(0)" ::: "memory");
  }
#undef VM
}

extern "C" void kernel_launch(void* const* d_in, const int* in_sizes, int n_in,
                              void* d_out, int out_size, void* d_ws, size_t ws_size,
                              hipStream_t stream) {
  const float* x = (const float*)d_in[0];
  const float* w = (const float*)d_in[1];
  const float* b = (const float*)d_in[2];
  float* out = (float*)d_out;

  char* ws = (char*)d_ws;
  float* amax = (float*)ws;                             // 3 floats
  float* bdeq = (float*)(ws + 256);                     // 4 KB
  float* px   = (float*)(ws + 8192);                    // 2048 partials
  float* pw   = (float*)(ws + 16384 + 8192);            // 256 partials
  signed char* qw = (signed char*)(ws + 65536);         // 1 MB
  signed char* qx = (signed char*)(ws + (1 << 21));     // 16 MB

  const int NPX = 2048, NPW = 256;
  hipLaunchKernelGGL(amax_both, dim3(NPX + NPW), dim3(256), 0, stream, x, w, px, pw);
  hipLaunchKernelGGL(finalize_kernel, dim3(1), dim3(256), 0, stream, px, NPX, pw, NPW, b, amax, bdeq);
  hipLaunchKernelGGL(quant_both, dim3(NPX + NPW), dim3(256), 0, stream, x, w, qx, qw, amax);

  // diagnostics first (read-only, no output writes), real gemm last
  hipLaunchKernelGGL((gemm_t<1, 3>), dim3(512), dim3(256), 0, stream, qx, qw, amax, bdeq, out);
  hipLaunchKernelGGL((gemm_t<2, 5>), dim3(512), dim3(256), 0, stream, qx, qw, amax, bdeq, out);
  hipLaunchKernelGGL((gemm_t<0, 1>), dim3(512), dim3(256), 0, stream, qx, qw, amax, bdeq, out);
}

// Round 14
// 58.300 us; speedup vs baseline: 2.4681x; 2.4681x over previous
//
#include <hip/hip_runtime.h>

// AdaPT_Linear: per-tensor int8 quantized linear.
// out = (qx @ qw^T).f32 / (sa*sw) + qb.f32/sb
// x: [16384,1024] f32, w: [1024,1024] f32, b: [1024] f32, out: [16384,1024] f32

#define M_ROWS 16384
#define K_DIM  1024
#define N_OUT  1024

typedef int v4i __attribute__((ext_vector_type(4)));
typedef float v4f __attribute__((ext_vector_type(4)));

__device__ __forceinline__ void gload_lds16(const void* g, void* l) {
  __builtin_amdgcn_global_load_lds(
      (const __attribute__((address_space(1))) void*)g,
      (__attribute__((address_space(3))) void*)l, 16, 0, 0);
}

__device__ __forceinline__ float block_reduce_max4(float m, float* red) {
#pragma unroll
  for (int off = 32; off > 0; off >>= 1)
    m = fmaxf(m, __shfl_down(m, off));
  const int wid = threadIdx.x >> 6, lane = threadIdx.x & 63;
  if (lane == 0) red[wid] = m;
  __syncthreads();
  float r = fmaxf(fmaxf(red[0], red[1]), fmaxf(red[2], red[3]));
  __syncthreads();
  return r;
}

// fused: blocks [0,2048) reduce x -> px, blocks [2048,2304) reduce w -> pw
__global__ void amax_both(const float* __restrict__ x, const float* __restrict__ wsrc,
                          float* __restrict__ px, float* __restrict__ pw) {
  __shared__ float red[4];
  const bool isx = blockIdx.x < 2048;
  const float* src = isx ? x : wsrc;
  const int n4   = isx ? (M_ROWS * K_DIM / 4) : (N_OUT * K_DIM / 4);
  const int nblk = isx ? 2048 : 256;
  const int bidl = isx ? blockIdx.x : blockIdx.x - 2048;
  float m = 0.0f;
  const int stride = nblk * 256;
  for (int idx = bidl * 256 + threadIdx.x; idx < n4; idx += stride) {
    float4 v = ((const float4*)src)[idx];
    m = fmaxf(m, fmaxf(fmaxf(fabsf(v.x), fabsf(v.y)), fmaxf(fabsf(v.z), fabsf(v.w))));
  }
  float r = block_reduce_max4(m, red);
  if (threadIdx.x == 0) (isx ? px : pw)[bidl] = r;
}

__global__ void finalize_kernel(const float* __restrict__ px, int npx,
                                const float* __restrict__ pw, int npw,
                                const float* __restrict__ bias,
                                float* __restrict__ amax,
                                float* __restrict__ bdeq) {
  __shared__ float red[4];
  const int tid = threadIdx.x;

  float m = 0.0f;
  for (int i = tid; i < npx; i += 256) m = fmaxf(m, px[i]);
  float rx = block_reduce_max4(m, red);

  m = 0.0f;
  for (int i = tid; i < npw; i += 256) m = fmaxf(m, pw[i]);
  float rw = block_reduce_max4(m, red);

  float4 bv = ((const float4*)bias)[tid];  // 256*4 == 1024 exactly
  m = fmaxf(fmaxf(fabsf(bv.x), fabsf(bv.y)), fmaxf(fabsf(bv.z), fabsf(bv.w)));
  float rb = block_reduce_max4(m, red);

  if (rx == 0.0f) rx = 1.0f;
  if (rw == 0.0f) rw = 1.0f;
  if (rb == 0.0f) rb = 1.0f;
  if (tid == 0) {
    amax[0] = rx;
    amax[1] = rw;
    amax[2] = rb;
  }
  const float sb = 127.0f / rb;
  float4 q;
  q.x = fminf(fmaxf(rintf(sb * bv.x), -127.0f), 127.0f) / sb;
  q.y = fminf(fmaxf(rintf(sb * bv.y), -127.0f), 127.0f) / sb;
  q.z = fminf(fmaxf(rintf(sb * bv.z), -127.0f), 127.0f) / sb;
  q.w = fminf(fmaxf(rintf(sb * bv.w), -127.0f), 127.0f) / sb;
  ((float4*)bdeq)[tid] = q;
}

// fused: blocks [0,2048) quantize x -> qx, [2048,2304) w -> qw
__global__ void quant_both(const float* __restrict__ x, const float* __restrict__ wsrc,
                           signed char* __restrict__ qx, signed char* __restrict__ qw,
                           const float* __restrict__ amax) {
  const bool isx = blockIdx.x < 2048;
  const float* src = isx ? x : wsrc;
  signed char* dst = isx ? qx : qw;
  const int n4   = isx ? (M_ROWS * K_DIM / 4) : (N_OUT * K_DIM / 4);
  const int nblk = isx ? 2048 : 256;
  const int bidl = isx ? blockIdx.x : blockIdx.x - 2048;
  const float s = 127.0f / amax[isx ? 0 : 1];
  const int stride = nblk * 256;
  for (int idx = bidl * 256 + threadIdx.x; idx < n4; idx += stride) {
    float4 v = ((const float4*)src)[idx];
    int q0 = (int)fminf(fmaxf(rintf(s * v.x), -127.0f), 127.0f);
    int q1 = (int)fminf(fmaxf(rintf(s * v.y), -127.0f), 127.0f);
    int q2 = (int)fminf(fmaxf(rintf(s * v.z), -127.0f), 127.0f);
    int q3 = (int)fminf(fmaxf(rintf(s * v.w), -127.0f), 127.0f);
    unsigned int packed = (q0 & 0xff) | ((q1 & 0xff) << 8) |
                          ((q2 & 0xff) << 16) | ((q3 & 0xff) << 24);
    ((unsigned int*)dst)[idx] = packed;
  }
}

// ---------------------------------------------------------------------------
// i8 GEMM, 256x128 tile, BK=64, 4 waves (2Mx2N, wave=128x64), TRIPLE-buffered
// LDS (3 x 24KB = 72KB, 2 blocks/CU), ONE barrier per K-step.
// R13 bug fixed: barrier must come AFTER the per-wave VM(6) — vmcnt is
// wave-local, so only {all waves pass VM(6)} -> BAR publishes every wave's
// slice of tile kt. Correct order per kt:
//   {STG(tile kt+1 -> pS); VM(6); BAR; 12 ds_read(pR); 32 MFMA}   (no tail
//   LGKM0/BAR: with 3 bufs, STG at kt targets buffer last read at kt-2;
//   those ds_reads drained before MFMA(kt-2) (compiler lgkmcnt), which
//   precedes reader's BAR(kt-1); stager writes after its BAR(kt-1). Safe.)
// RAW: at kt outstanding = 6(tile kt) + 6(just-issued kt+1); VM(6) drains
// tile kt; BAR publishes. Tail: VM(0). Prologue: STG(buf0, tile0).
// Swizzle: stored unit = gunit ^ ((row>>1)&3) via pre-swizzled source +
// swizzled ds_read (involution); frag reads conflict-free (8 grp x 2 lanes).
// Epilogue: per-wave LDS transpose + nontemporal v4f stores (R9).
// ---------------------------------------------------------------------------
#define NKT 16

__global__ __launch_bounds__(256, 2) void gemm_kernel(
    const signed char* __restrict__ qx, const signed char* __restrict__ qw,
    const float* __restrict__ amax, const float* __restrict__ bdeq,
    float* __restrict__ out) {
  __shared__ char lds[73728];  // 3 bufs x 24KB (A 16K + B 8K each)

  const int tid  = threadIdx.x;
  const int w    = tid >> 6;
  const int lane = tid & 63;
  const int wm = w >> 1;
  const int wn = w & 1;
  const int fr = lane & 15;
  const int q  = lane >> 4;

  // XCD-aware swizzle (grid 512 = 8 XCDs x 64 contiguous)
  const int bid = blockIdx.x;
  const int wg  = (bid & 7) * 64 + (bid >> 3);
  const int Mbase = (wg >> 3) * 256;
  const int Nbase = (wg & 7) * 128;

  const signed char* gA = qx + (size_t)Mbase * K_DIM;
  const signed char* gB = qw + (size_t)Nbase * K_DIM;

  const int srow = tid >> 2;                       // 0..63
  const int scol = ((tid & 3) ^ ((tid >> 3) & 3)) << 4;
  const int u0    = (q ^ ((fr >> 1) & 3)) << 4;
  const int aoffA = fr * 64 + u0;
  const int aoffB = fr * 64 + u0;

  const float inv_denom = (amax[0] * amax[1]) * (1.0f / 16129.0f);

  v4i acc[8][4] = {};
  v4i Ar[8], Br[4];

#define STG(BASE, T)                                                           \
  do {                                                                         \
    const int _k0 = (T)*64 + scol;                                             \
    char* _la = (BASE);                                                        \
    char* _lb = (BASE) + 16384;                                                \
    _Pragma("unroll") for (int i = 0; i < 4; ++i)                              \
      gload_lds16(gA + (size_t)(i * 64 + srow) * K_DIM + _k0,                  \
                  _la + i * 4096 + tid * 16);                                  \
    _Pragma("unroll") for (int i = 0; i < 2; ++i)                              \
      gload_lds16(gB + (size_t)(i * 64 + srow) * K_DIM + _k0,                  \
                  _lb + i * 4096 + tid * 16);                                  \
  } while (0)

#define VM(N) asm volatile("s_waitcnt vmcnt(" #N ")" ::: "memory")
#define LGKM0() asm volatile("s_waitcnt lgkmcnt(0)" ::: "memory")

  char* pR = lds;           // read buffer (tile kt)
  char* pS = lds + 24576;   // stage target (tile kt+1)
  char* pF = lds + 49152;   // staged next iter (read at kt+2)

  STG(pR, 0);  // prologue: tile 0

#pragma unroll
  for (int kt = 0; kt < NKT; ++kt) {
    if (kt + 1 < NKT) {
      STG(pS, kt + 1);
      VM(6);  // this wave's tile-kt loads landed (6 just-issued remain)
    } else {
      VM(0);
    }
    __builtin_amdgcn_s_barrier();  // publish all waves' slices of tile kt

    const char* _A = pR + wm * 8192;
    const char* _B = pR + 16384 + wn * 4096;
#pragma unroll
    for (int f = 0; f < 8; ++f)
      Ar[f] = *(const v4i*)(_A + aoffA + f * 1024);
#pragma unroll
    for (int g = 0; g < 4; ++g)
      Br[g] = *(const v4i*)(_B + aoffB + g * 1024);
#pragma unroll
    for (int f = 0; f < 8; ++f)
#pragma unroll
      for (int g = 0; g < 4; ++g)
        acc[f][g] = __builtin_amdgcn_mfma_i32_16x16x64_i8(Ar[f], Br[g], acc[f][g], 0, 0, 0);

    char* t = pR; pR = pS; pS = pF; pF = t;  // rotate
  }
#undef STG

  // ------------------------ epilogue (store-path) --------------------------
  __syncthreads();  // final tile reads drained (pre-MFMA lgkmcnt); repurpose

  float bdq[4];
#pragma unroll
  for (int g = 0; g < 4; ++g) bdq[g] = bdeq[Nbase + wn * 64 + g * 16 + fr];

  float* lws = (float*)(lds + w * 12288);  // 16x66 f32 per wave

  const int erow = lane >> 4;
  const int ecg  = lane & 15;
  float* const orow_base = out + (size_t)(Mbase + wm * 128) * N_OUT +
                           (Nbase + wn * 64) + ecg * 4;

#pragma unroll
  for (int f = 0; f < 8; ++f) {
#pragma unroll
    for (int g = 0; g < 4; ++g)
#pragma unroll
      for (int i = 0; i < 4; ++i)
        lws[(q * 4 + i) * 66 + g * 16 + fr] =
            (float)acc[f][g][i] * inv_denom + bdq[g];
    LGKM0();  // wave-local ordering
#pragma unroll
    for (int t = 0; t < 4; ++t) {
      const int r16 = t * 4 + erow;
      v4f v = *(const v4f*)&lws[r16 * 66 + ecg * 4];
      __builtin_nontemporal_store(
          v, (v4f*)(orow_base + (size_t)(f * 16 + r16) * N_OUT));
    }
    LGKM0();  // reads done before overwrite
  }
#undef VM
#undef LGKM0
}

extern "C" void kernel_launch(void* const* d_in, const int* in_sizes, int n_in,
                              void* d_out, int out_size, void* d_ws, size_t ws_size,
                              hipStream_t stream) {
  const float* x = (const float*)d_in[0];
  const float* w = (const float*)d_in[1];
  const float* b = (const float*)d_in[2];
  float* out = (float*)d_out;

  char* ws = (char*)d_ws;
  float* amax = (float*)ws;                             // 3 floats
  float* bdeq = (float*)(ws + 256);                     // 4 KB
  float* px   = (float*)(ws + 8192);                    // 2048 partials
  float* pw   = (float*)(ws + 16384 + 8192);            // 256 partials
  signed char* qw = (signed char*)(ws + 65536);         // 1 MB
  signed char* qx = (signed char*)(ws + (1 << 21));     // 16 MB

  const int NPX = 2048, NPW = 256;
  hipLaunchKernelGGL(amax_both, dim3(NPX + NPW), dim3(256), 0, stream, x, w, px, pw);
  hipLaunchKernelGGL(finalize_kernel, dim3(1), dim3(256), 0, stream, px, NPX, pw, NPW, b, amax, bdeq);
  hipLaunchKernelGGL(quant_both, dim3(NPX + NPW), dim3(256), 0, stream, x, w, qx, qw, amax);
  hipLaunchKernelGGL(gemm_kernel, dim3(128 * 4), dim3(256), 0, stream, qx, qw, amax, bdeq, out);
}